// Round 4
// baseline (804.378 us; speedup 1.0000x reference)
//
#include <hip/hip_runtime.h>
#include <hip/hip_bf16.h>

// Problem constants
#define BB 8
#define SS 2048
#define HD 512   // H*DK
#define DM 512

typedef __attribute__((ext_vector_type(8))) short short8;   // 8 bf16
typedef __attribute__((ext_vector_type(4))) short short4v;  // 4 bf16 (mfma 16x16x16 A/B)
typedef __attribute__((ext_vector_type(4))) float floatx4;  // MFMA C/D

__device__ __forceinline__ short f2bf(float f) {
    __hip_bfloat16 h = __float2bfloat16(f);  // RNE
    short s;
    __builtin_memcpy(&s, &h, 2);
    return s;
}

__device__ __forceinline__ uint2 pack4bf(float a, float b, float cc, float d) {
    __hip_bfloat162 lo = __float22bfloat162_rn(float2{a, b});
    __hip_bfloat162 hi = __float22bfloat162_rn(float2{cc, d});
    uint2 r;
    __builtin_memcpy(&r.x, &lo, 4);
    __builtin_memcpy(&r.y, &hi, 4);
    return r;
}

__device__ __forceinline__ short4v pack4bf_s4(float a, float b, float cc, float d) {
    uint2 u = pack4bf(a, b, cc, d);
    short4v s;
    __builtin_memcpy(&s, &u, 8);
    return s;
}

__device__ __forceinline__ floatx4 mfma16(short4v a, short4v b, floatx4 c) {
#if __has_builtin(__builtin_amdgcn_mfma_f32_16x16x16_bf16)
    return __builtin_amdgcn_mfma_f32_16x16x16_bf16(a, b, c, 0, 0, 0);
#else
    return __builtin_amdgcn_mfma_f32_16x16x16bf16_1k(a, b, c, 0, 0, 0);
#endif
}

// ---------------------------------------------------------------------------
// prep: build WqT[512][64], WoT[512][512] (bf16, transposed)
// ---------------------------------------------------------------------------
__global__ void prep_kernel(const float* __restrict__ Wq, const float* __restrict__ Wo,
                            short* __restrict__ WqT, short* __restrict__ WoT) {
    int idx = blockIdx.x * 256 + threadIdx.x;             // 0 .. 262143
    if (idx < HD * 64) {                                  // 32768
        int o = idx >> 6, i = idx & 63;
        WqT[idx] = f2bf(Wq[i * HD + o]);
    }
    {
        int o = idx >> 9, i = idx & 511;
        WoT[idx] = f2bf(Wo[i * DM + o]);
    }
}

// ---------------------------------------------------------------------------
// maskbits: bit=1 where mask==1.0 (those get -inf). 4 ballots per wave.
// ---------------------------------------------------------------------------
__global__ void maskbits_kernel(const float* __restrict__ mask,
                                unsigned long long* __restrict__ bits) {
    int gw = blockIdx.x * 4 + (threadIdx.x >> 6);
    int lane = threadIdx.x & 63;
    size_t base = (size_t)gw * 256;
#pragma unroll
    for (int j = 0; j < 4; ++j) {
        float val = mask[base + j * 64 + lane];
        unsigned long long bal = __ballot(val == 1.0f);
        if (lane == 0) bits[gw * 4 + j] = bal;
    }
}

// ---------------------------------------------------------------------------
// Generic C = alpha*(A * B^T + bias).  A:[M][K] row-major, Bt:[N][K] row-major.
// SMODE: 0 = fp32 natural, 1 = bf16 natural, 2 = K-swizzled (khS), 3 = V-interleaved (vI)
// khS layout: [b*8+h][s][ (dg ^ (s&7))*8 + d&7 ]        (dg = d>>3, d = col&63)
// vI  layout: [b*8+h][s>>3][ (d ^ ((s>>3)&15))*8 + s&7 ] (d = row&63)
// ---------------------------------------------------------------------------
template <int SMODE, bool BIAS_ROW, bool A_F32, bool B_F32>
__global__ __launch_bounds__(256, 2) void gemm_bt(
    const void* __restrict__ A_, int lda, long sA,
    const void* __restrict__ B_, int ldb, long sB,
    void* __restrict__ C, int ldc, long sC,
    const float* __restrict__ bias, int K, float alpha) {
    const int bz = blockIdx.z;
    const int m0 = blockIdx.y * 128, n0 = blockIdx.x * 128;
    __shared__ __align__(16) short As[128 * 80];
    __shared__ __align__(16) short Bs[128 * 80];
    const int tid = threadIdx.x, lane = tid & 63, w = tid >> 6;
    const int c = lane & 15, Q = lane >> 4;
    const int wm = w >> 1, wn = w & 1;
    floatx4 acc[4][4] = {};

    for (int k0 = 0; k0 < K; k0 += 64) {
#pragma unroll
        for (int it = 0; it < 4; ++it) {
            int chunk = it * 256 + tid;
            int row = chunk >> 3, c8 = chunk & 7;
            size_t aoff = (size_t)bz * sA + (size_t)(m0 + row) * lda + k0 + c8 * 8;
            size_t boff = (size_t)bz * sB + (size_t)(n0 + row) * ldb + k0 + c8 * 8;
            if (A_F32) {
                const float* Af = (const float*)A_ + aoff;
                float4 lo = *(const float4*)Af;
                float4 hi = *(const float4*)(Af + 4);
                uint2 p0 = pack4bf(lo.x, lo.y, lo.z, lo.w);
                uint2 p1 = pack4bf(hi.x, hi.y, hi.z, hi.w);
                *(uint4*)&As[row * 80 + c8 * 8] = uint4{p0.x, p0.y, p1.x, p1.y};
            } else {
                *(uint4*)&As[row * 80 + c8 * 8] = *(const uint4*)((const short*)A_ + aoff);
            }
            if (B_F32) {
                const float* Bf = (const float*)B_ + boff;
                float4 lo = *(const float4*)Bf;
                float4 hi = *(const float4*)(Bf + 4);
                uint2 p0 = pack4bf(lo.x, lo.y, lo.z, lo.w);
                uint2 p1 = pack4bf(hi.x, hi.y, hi.z, hi.w);
                *(uint4*)&Bs[row * 80 + c8 * 8] = uint4{p0.x, p0.y, p1.x, p1.y};
            } else {
                *(uint4*)&Bs[row * 80 + c8 * 8] = *(const uint4*)((const short*)B_ + boff);
            }
        }
        __syncthreads();
#pragma unroll
        for (int ks = 0; ks < 2; ++ks) {
            short8 af[4], bf[4];
#pragma unroll
            for (int mt = 0; mt < 4; ++mt)
                af[mt] = *(const short8*)&As[(wm * 64 + mt * 16 + c) * 80 + ks * 32 + 8 * Q];
#pragma unroll
            for (int nt = 0; nt < 4; ++nt)
                bf[nt] = *(const short8*)&Bs[(wn * 64 + nt * 16 + c) * 80 + ks * 32 + 8 * Q];
#pragma unroll
            for (int mt = 0; mt < 4; ++mt)
#pragma unroll
                for (int nt = 0; nt < 4; ++nt)
                    acc[mt][nt] = __builtin_amdgcn_mfma_f32_16x16x32_bf16(
                        af[mt], bf[nt], acc[mt][nt], 0, 0, 0);
        }
        __syncthreads();
    }
#pragma unroll
    for (int mt = 0; mt < 4; ++mt)
#pragma unroll
        for (int nt = 0; nt < 4; ++nt) {
            int col = n0 + wn * 64 + nt * 16 + c;
            float bc = BIAS_ROW ? 0.f : bias[col];
#pragma unroll
            for (int r = 0; r < 4; ++r) {
                int row = m0 + wm * 64 + mt * 16 + 4 * Q + r;
                float val = (acc[mt][nt][r] + (BIAS_ROW ? bias[row] : bc)) * alpha;
                if (SMODE == 0) {
                    ((float*)C)[(size_t)bz * sC + (size_t)row * ldc + col] = val;
                } else if (SMODE == 1) {
                    ((short*)C)[(size_t)bz * sC + (size_t)row * ldc + col] = f2bf(val);
                } else if (SMODE == 2) {
                    // row = b*2048 + s (M=16384), col = hd
                    int b = row >> 11, s = row & 2047, h = col >> 6, d = col & 63;
                    size_t idx = ((size_t)(b * 8 + h)) * 131072 + (size_t)s * 64 +
                                 (size_t)(((d >> 3) ^ (s & 7)) * 8 + (d & 7));
                    ((short*)C)[idx] = f2bf(val);
                } else {
                    // row = hd (M=512), col = s (N=2048), b = bz
                    int h = row >> 6, d = row & 63, s = col;
                    size_t idx = ((size_t)(bz * 8 + h)) * 131072 + (size_t)(s >> 3) * 512 +
                                 (size_t)((d ^ ((s >> 3) & 15)) * 8 + (s & 7));
                    ((short*)C)[idx] = f2bf(val);
                }
            }
        }
}

// ---------------------------------------------------------------------------
// Flash attention. Block = 256 thr (4 waves), q=32/wave -> qtile 128, ktile 128.
// S^T = K*Q^T (16x16x32); P feeds PV directly as A-operand of 16x16x16 MFMA.
// XCD-aware 1D grid: id = (bh&7) + 8*((bh>>3)*16 + qt) -> id%8 = bh&7, so each
// XCD's L2 serves exactly 8 bh slices (8 x 512KB = 4MB = L2 size).
// Register double-buffer: next kt's K/V tiles prefetched into VGPRs during
// compute, written to LDS after the barrier (hides staging latency).
// ---------------------------------------------------------------------------
__global__ __launch_bounds__(256, 4) void fa_kernel(
    const short* __restrict__ qh, const short* __restrict__ khS,
    const short* __restrict__ vI, const unsigned* __restrict__ mbits,
    short* __restrict__ y) {
    const int id = blockIdx.x;          // 0..1023
    const int xcd = id & 7, slot = id >> 3;
    const int qt = slot & 15;           // 128 q-rows each
    const int bh = (slot >> 4) * 8 + xcd;
    const int b = bh >> 3, h = bh & 7;
    const int tid = threadIdx.x, lane = tid & 63, w = tid >> 6;   // w 0..3
    const int c = lane & 15, Q = lane >> 4;
    const int c7 = c & 7;

    __shared__ __align__(16) short Ks[8192];   // 16 KB swizzled K tile
    __shared__ __align__(16) short Vs[8192];   // 16 KB interleaved V tile

    // Q fragments: 2 sub-tiles (t) x 2 k-halves, loop-invariant, from global
    const int qbase0 = qt * 128 + w * 32;      // + t*16 + c = q row
    short8 qf[2][2];
#pragma unroll
    for (int t = 0; t < 2; ++t) {
        const short* qb = qh + ((size_t)(b * SS + qbase0 + t * 16 + c)) * HD + h * 64;
        qf[t][0] = *(const short8*)(qb + 8 * Q);
        qf[t][1] = *(const short8*)(qb + 32 + 8 * Q);
    }
    const unsigned* mrow[2] = {
        mbits + (size_t)(b * SS + qbase0 + c) * 64,
        mbits + (size_t)(b * SS + qbase0 + 16 + c) * 64};

    const short* kbase = khS + (size_t)bh * 131072;
    const short* vbase = vI + (size_t)bh * 131072;

    floatx4 o[2][4] = {};
    float m_i[2] = {-INFINITY, -INFINITY}, l_i[2] = {0.f, 0.f};

    // ---- prologue: stage kt=0 tiles ----
    uint4 kbuf[4], vbuf[4];
#pragma unroll
    for (int it = 0; it < 4; ++it) {
        int off = (it * 256 + tid) * 8;
        kbuf[it] = *(const uint4*)(kbase + off);
        vbuf[it] = *(const uint4*)(vbase + off);
    }
#pragma unroll
    for (int it = 0; it < 4; ++it) {
        int off = (it * 256 + tid) * 8;
        *(uint4*)&Ks[off] = kbuf[it];
        *(uint4*)&Vs[off] = vbuf[it];
    }
    __syncthreads();

    for (int kt = 0; kt < 16; ++kt) {
        // ---- prefetch kt+1 tiles into registers (no wait until after compute) ----
        if (kt < 15) {
            const short* kg = kbase + (kt + 1) * 8192;
            const short* vg = vbase + (kt + 1) * 8192;
#pragma unroll
            for (int it = 0; it < 4; ++it) {
                int off = (it * 256 + tid) * 8;
                kbuf[it] = *(const uint4*)(kg + off);
                vbuf[it] = *(const uint4*)(vg + off);
            }
        }
        uint4 mr[2];
#pragma unroll
        for (int t = 0; t < 2; ++t) mr[t] = *(const uint4*)(mrow[t] + kt * 4);

        // ---- S^T = K Q^T for both q-subtiles; K-frags read once ----
        floatx4 s[2][8];
        float mx[2] = {-INFINITY, -INFINITY};
#pragma unroll
        for (int jt = 0; jt < 8; ++jt) {
            short8 k0 = *(const short8*)&Ks[(16 * jt + c) * 64 + ((Q) ^ c7) * 8];
            short8 k1 = *(const short8*)&Ks[(16 * jt + c) * 64 + ((Q + 4) ^ c7) * 8];
#pragma unroll
            for (int t = 0; t < 2; ++t) {
                floatx4 z = {};
                z = __builtin_amdgcn_mfma_f32_16x16x32_bf16(k0, qf[t][0], z, 0, 0, 0);
                z = __builtin_amdgcn_mfma_f32_16x16x32_bf16(k1, qf[t][1], z, 0, 0, 0);
                unsigned mwd = (jt & 2) ? ((jt & 4) ? mr[t].w : mr[t].y)
                                        : ((jt & 4) ? mr[t].z : mr[t].x);
                unsigned nib = (mwd >> (((jt & 1) << 4) + 4 * Q)) & 0xFu;
#pragma unroll
                for (int r = 0; r < 4; ++r) {
                    float val = (nib & (1u << r)) ? -INFINITY : z[r];
                    z[r] = val;
                    mx[t] = fmaxf(mx[t], val);
                }
                s[t][jt] = z;
            }
        }

        // ---- online softmax state update (per-lane; quad-reduce) ----
        float al[2], msafe[2];
#pragma unroll
        for (int t = 0; t < 2; ++t) {
            float m = mx[t];
            m = fmaxf(m, __shfl_xor(m, 16));
            m = fmaxf(m, __shfl_xor(m, 32));
            float mnew = fmaxf(m_i[t], m);
            msafe[t] = (mnew == -INFINITY) ? 0.f : mnew;
            al[t] = __builtin_amdgcn_exp2f(m_i[t] - msafe[t]);
            m_i[t] = mnew;
            // rescale O: need al for q-local 4Q+r (state lives at lane c==4Q+r)
#pragma unroll
            for (int r = 0; r < 4; ++r) {
                float alr = __shfl(al[t], 4 * Q + r);
#pragma unroll
                for (int nt = 0; nt < 4; ++nt) o[t][nt][r] *= alr;
            }
        }

        // ---- P = exp2(S - m); feed directly into PV (16x16x16 MFMA) ----
        float ps[2] = {0.f, 0.f};
#pragma unroll
        for (int jt = 0; jt < 8; ++jt) {
            short4v af[2];
#pragma unroll
            for (int t = 0; t < 2; ++t) {
                float p0 = __builtin_amdgcn_exp2f(s[t][jt][0] - msafe[t]);
                float p1 = __builtin_amdgcn_exp2f(s[t][jt][1] - msafe[t]);
                float p2 = __builtin_amdgcn_exp2f(s[t][jt][2] - msafe[t]);
                float p3 = __builtin_amdgcn_exp2f(s[t][jt][3] - msafe[t]);
                ps[t] += (p0 + p1) + (p2 + p3);
                af[t] = pack4bf_s4(p0, p1, p2, p3);
            }
            const int g = 2 * jt + (Q >> 1);
            const int i4 = 4 * (Q & 1);
#pragma unroll
            for (int nt = 0; nt < 4; ++nt) {
                short4v vf = *(const short4v*)&Vs[g * 512 + ((16 * nt + c) ^ g) * 8 + i4];
                o[0][nt] = mfma16(af[0], vf, o[0][nt]);
                o[1][nt] = mfma16(af[1], vf, o[1][nt]);
            }
        }
#pragma unroll
        for (int t = 0; t < 2; ++t) {
            float p = ps[t];
            p += __shfl_xor(p, 16);
            p += __shfl_xor(p, 32);
            l_i[t] = l_i[t] * al[t] + p;
        }
        __syncthreads();   // all waves done reading Ks/Vs

        // ---- write prefetched tiles to LDS (waitcnt auto-inserted here) ----
        if (kt < 15) {
#pragma unroll
            for (int it = 0; it < 4; ++it) {
                int off = (it * 256 + tid) * 8;
                *(uint4*)&Ks[off] = kbuf[it];
                *(uint4*)&Vs[off] = vbuf[it];
            }
        }
        __syncthreads();
    }

    // ---- epilogue: O/l -> y bf16 ----
#pragma unroll
    for (int t = 0; t < 2; ++t) {
#pragma unroll
        for (int r = 0; r < 4; ++r) {
            float lr = __shfl(l_i[t], 4 * Q + r);
            float inv = 1.0f / lr;
            int row = qbase0 + t * 16 + 4 * Q + r;
#pragma unroll
            for (int nt = 0; nt < 4; ++nt)
                y[((size_t)(b * SS + row)) * HD + h * 64 + 16 * nt + c] =
                    f2bf(o[t][nt][r] * inv);
        }
    }
}

// ---------------------------------------------------------------------------
extern "C" void kernel_launch(void* const* d_in, const int* in_sizes, int n_in,
                              void* d_out, int out_size, void* d_ws, size_t ws_size,
                              hipStream_t stream) {
    const float* q    = (const float*)d_in[0];
    const float* k    = (const float*)d_in[1];
    const float* v    = (const float*)d_in[2];
    const float* mask = (const float*)d_in[3];
    const float* Wq   = (const float*)d_in[4];
    const float* bq   = (const float*)d_in[5];
    const float* Wo   = (const float*)d_in[6];
    const float* bo   = (const float*)d_in[7];

    char* ws = (char*)d_ws;
    const size_t MB = 1ull << 20;
    short* WqT = (short*)(ws + 0 * MB);    // 64 KB
    short* WoT = (short*)(ws + 1 * MB);    // 512 KB
    short* qh  = (short*)(ws + 8 * MB);    // 16 MB  [b][s][hd], pre-scaled log2e/8
    short* khS = (short*)(ws + 24 * MB);   // 16 MB  swizzled [bh][s][dg^s&7][8]
    short* vI  = (short*)(ws + 40 * MB);   // 16 MB  interleaved [bh][s8][d^sg][8]
    unsigned long long* bits = (unsigned long long*)(ws + 56 * MB);  // 4 MB
    short* yb  = (short*)(ws + 60 * MB);   // 16 MB  [b][s][hd]
    float* out = (float*)d_out;

    const float ALPHA_Q = 0.18033688011f;  // log2(e)/8

    prep_kernel<<<1024, 256, 0, stream>>>(Wq, Wo, WqT, WoT);
    maskbits_kernel<<<32768, 256, 0, stream>>>(mask, bits);

    // qh = (q @ Wq + bq) * alpha   (natural layout)
    gemm_bt<1, false, true, false><<<dim3(4, 128, 1), 256, 0, stream>>>(
        q, 64, 0, WqT, 64, 0, (void*)qh, 512, 0, bq, 64, ALPHA_Q);
    // khS = swizzled(k @ Wq + bq)
    gemm_bt<2, false, true, false><<<dim3(4, 128, 1), 256, 0, stream>>>(
        k, 64, 0, WqT, 64, 0, (void*)khS, 0, 0, bq, 64, 1.0f);
    // vI = interleaved(WqT @ v^T + bq), batched over b
    gemm_bt<3, true, false, true><<<dim3(16, 4, BB), 256, 0, stream>>>(
        WqT, 64, 0, v, 64, (long)SS * 64, (void*)vI, 0, 0, bq, 64, 1.0f);

    fa_kernel<<<dim3(1024, 1, 1), 256, 0, stream>>>(qh, khS, vI, (const unsigned*)bits, yb);

    // out = y @ Wo + bo  (fp32)
    gemm_bt<0, false, false, false><<<dim3(4, 128, 1), 256, 0, stream>>>(
        yb, 512, 0, WoT, 512, 0, (void*)out, 512, 0, bo, 512, 1.0f);
}

// Round 5
// 420.414 us; speedup vs baseline: 1.9133x; 1.9133x over previous
//
#include <hip/hip_runtime.h>
#include <hip/hip_bf16.h>

// Problem constants
#define BB 8
#define SS 2048
#define HD 512   // H*DK
#define DM 512

typedef __attribute__((ext_vector_type(8))) short short8;   // 8 bf16
typedef __attribute__((ext_vector_type(4))) short short4v;  // 4 bf16 (mfma 16x16x16 A/B)
typedef __attribute__((ext_vector_type(4))) float floatx4;  // MFMA C/D

__device__ __forceinline__ short f2bf(float f) {
    __hip_bfloat16 h = __float2bfloat16(f);  // RNE
    short s;
    __builtin_memcpy(&s, &h, 2);
    return s;
}

__device__ __forceinline__ uint2 pack4bf(float a, float b, float cc, float d) {
    __hip_bfloat162 lo = __float22bfloat162_rn(float2{a, b});
    __hip_bfloat162 hi = __float22bfloat162_rn(float2{cc, d});
    uint2 r;
    __builtin_memcpy(&r.x, &lo, 4);
    __builtin_memcpy(&r.y, &hi, 4);
    return r;
}

__device__ __forceinline__ short4v pack4bf_s4(float a, float b, float cc, float d) {
    uint2 u = pack4bf(a, b, cc, d);
    short4v s;
    __builtin_memcpy(&s, &u, 8);
    return s;
}

__device__ __forceinline__ floatx4 mfma16(short4v a, short4v b, floatx4 c) {
#if __has_builtin(__builtin_amdgcn_mfma_f32_16x16x16_bf16)
    return __builtin_amdgcn_mfma_f32_16x16x16_bf16(a, b, c, 0, 0, 0);
#else
    return __builtin_amdgcn_mfma_f32_16x16x16bf16_1k(a, b, c, 0, 0, 0);
#endif
}

// ---------------------------------------------------------------------------
// prep: build WqT[512][64], WoT[512][512] (bf16, transposed)
// ---------------------------------------------------------------------------
__global__ void prep_kernel(const float* __restrict__ Wq, const float* __restrict__ Wo,
                            short* __restrict__ WqT, short* __restrict__ WoT) {
    int idx = blockIdx.x * 256 + threadIdx.x;             // 0 .. 262143
    if (idx < HD * 64) {                                  // 32768
        int o = idx >> 6, i = idx & 63;
        WqT[idx] = f2bf(Wq[i * HD + o]);
    }
    {
        int o = idx >> 9, i = idx & 511;
        WoT[idx] = f2bf(Wo[i * DM + o]);
    }
}

// ---------------------------------------------------------------------------
// maskbits: bit=1 where mask==1.0 (those get -inf). 4 ballots per wave.
// ---------------------------------------------------------------------------
__global__ void maskbits_kernel(const float* __restrict__ mask,
                                unsigned long long* __restrict__ bits) {
    int gw = blockIdx.x * 4 + (threadIdx.x >> 6);
    int lane = threadIdx.x & 63;
    size_t base = (size_t)gw * 256;
#pragma unroll
    for (int j = 0; j < 4; ++j) {
        float val = mask[base + j * 64 + lane];
        unsigned long long bal = __ballot(val == 1.0f);
        if (lane == 0) bits[gw * 4 + j] = bal;
    }
}

// ---------------------------------------------------------------------------
// Generic C = alpha*(A * B^T + bias).  A:[M][K] row-major, Bt:[N][K] row-major.
// SMODE: 0 = fp32 natural, 1 = bf16 natural, 2 = K-swizzled (khS), 3 = V-interleaved (vI)
// khS layout: [b*8+h][s][ (dg ^ (s&7))*8 + d&7 ]        (dg = d>>3, d = col&63)
// vI  layout: [b*8+h][s>>3][ (d ^ ((s>>3)&15))*8 + s&7 ] (d = row&63)
// ---------------------------------------------------------------------------
template <int SMODE, bool BIAS_ROW, bool A_F32, bool B_F32>
__global__ __launch_bounds__(256, 2) void gemm_bt(
    const void* __restrict__ A_, int lda, long sA,
    const void* __restrict__ B_, int ldb, long sB,
    void* __restrict__ C, int ldc, long sC,
    const float* __restrict__ bias, int K, float alpha) {
    const int bz = blockIdx.z;
    const int m0 = blockIdx.y * 128, n0 = blockIdx.x * 128;
    __shared__ __align__(16) short As[128 * 80];
    __shared__ __align__(16) short Bs[128 * 80];
    const int tid = threadIdx.x, lane = tid & 63, w = tid >> 6;
    const int c = lane & 15, Q = lane >> 4;
    const int wm = w >> 1, wn = w & 1;
    floatx4 acc[4][4] = {};

    for (int k0 = 0; k0 < K; k0 += 64) {
#pragma unroll
        for (int it = 0; it < 4; ++it) {
            int chunk = it * 256 + tid;
            int row = chunk >> 3, c8 = chunk & 7;
            size_t aoff = (size_t)bz * sA + (size_t)(m0 + row) * lda + k0 + c8 * 8;
            size_t boff = (size_t)bz * sB + (size_t)(n0 + row) * ldb + k0 + c8 * 8;
            if (A_F32) {
                const float* Af = (const float*)A_ + aoff;
                float4 lo = *(const float4*)Af;
                float4 hi = *(const float4*)(Af + 4);
                uint2 p0 = pack4bf(lo.x, lo.y, lo.z, lo.w);
                uint2 p1 = pack4bf(hi.x, hi.y, hi.z, hi.w);
                *(uint4*)&As[row * 80 + c8 * 8] = uint4{p0.x, p0.y, p1.x, p1.y};
            } else {
                *(uint4*)&As[row * 80 + c8 * 8] = *(const uint4*)((const short*)A_ + aoff);
            }
            if (B_F32) {
                const float* Bf = (const float*)B_ + boff;
                float4 lo = *(const float4*)Bf;
                float4 hi = *(const float4*)(Bf + 4);
                uint2 p0 = pack4bf(lo.x, lo.y, lo.z, lo.w);
                uint2 p1 = pack4bf(hi.x, hi.y, hi.z, hi.w);
                *(uint4*)&Bs[row * 80 + c8 * 8] = uint4{p0.x, p0.y, p1.x, p1.y};
            } else {
                *(uint4*)&Bs[row * 80 + c8 * 8] = *(const uint4*)((const short*)B_ + boff);
            }
        }
        __syncthreads();
#pragma unroll
        for (int ks = 0; ks < 2; ++ks) {
            short8 af[4], bf[4];
#pragma unroll
            for (int mt = 0; mt < 4; ++mt)
                af[mt] = *(const short8*)&As[(wm * 64 + mt * 16 + c) * 80 + ks * 32 + 8 * Q];
#pragma unroll
            for (int nt = 0; nt < 4; ++nt)
                bf[nt] = *(const short8*)&Bs[(wn * 64 + nt * 16 + c) * 80 + ks * 32 + 8 * Q];
#pragma unroll
            for (int mt = 0; mt < 4; ++mt)
#pragma unroll
                for (int nt = 0; nt < 4; ++nt)
                    acc[mt][nt] = __builtin_amdgcn_mfma_f32_16x16x32_bf16(
                        af[mt], bf[nt], acc[mt][nt], 0, 0, 0);
        }
        __syncthreads();
    }
#pragma unroll
    for (int mt = 0; mt < 4; ++mt)
#pragma unroll
        for (int nt = 0; nt < 4; ++nt) {
            int col = n0 + wn * 64 + nt * 16 + c;
            float bc = BIAS_ROW ? 0.f : bias[col];
#pragma unroll
            for (int r = 0; r < 4; ++r) {
                int row = m0 + wm * 64 + mt * 16 + 4 * Q + r;
                float val = (acc[mt][nt][r] + (BIAS_ROW ? bias[row] : bc)) * alpha;
                if (SMODE == 0) {
                    ((float*)C)[(size_t)bz * sC + (size_t)row * ldc + col] = val;
                } else if (SMODE == 1) {
                    ((short*)C)[(size_t)bz * sC + (size_t)row * ldc + col] = f2bf(val);
                } else if (SMODE == 2) {
                    // row = b*2048 + s (M=16384), col = hd
                    int b = row >> 11, s = row & 2047, h = col >> 6, d = col & 63;
                    size_t idx = ((size_t)(b * 8 + h)) * 131072 + (size_t)s * 64 +
                                 (size_t)(((d >> 3) ^ (s & 7)) * 8 + (d & 7));
                    ((short*)C)[idx] = f2bf(val);
                } else {
                    // row = hd (M=512), col = s (N=2048), b = bz
                    int h = row >> 6, d = row & 63, s = col;
                    size_t idx = ((size_t)(bz * 8 + h)) * 131072 + (size_t)(s >> 3) * 512 +
                                 (size_t)((d ^ ((s >> 3) & 15)) * 8 + (s & 7));
                    ((short*)C)[idx] = f2bf(val);
                }
            }
        }
}

// ---------------------------------------------------------------------------
// Flash attention. Block = 512 thr (8 waves), q=32/wave -> qtile 256, ktile 128.
// S^T = K*Q^T (16x16x32); P feeds PV directly as A-operand of 16x16x16 MFMA
// (C-layout k=4Q+r matches A-frag k=4Q+j -- no transpose, no P-LDS).
// K and V tiles are flat 16KB LDS copies of pre-swizzled global layouts.
// XCD-aware 1D grid: id = (bh&7) + 8*((bh>>3)*8 + qt) -> id%8 = bh&7, so each
// XCD's L2 serves exactly 8 bh slices; the 8 q-blocks of a bh progress through
// kt in near-lockstep so the active K/V set per XCD stays << 4 MiB.
// NOTE: no persistent register prefetch (R4 spill lesson); staging is transient
// uint4 round-trips, overlapped across the 16 waves/CU.
// ---------------------------------------------------------------------------
__global__ __launch_bounds__(512, 2) void fa_kernel(
    const short* __restrict__ qh, const short* __restrict__ khS,
    const short* __restrict__ vI, const unsigned* __restrict__ mbits,
    short* __restrict__ y) {
    const int id = blockIdx.x;          // 0..511
    const int xcd = id & 7, slot = id >> 3;
    const int qt = slot & 7;            // 256 q-rows each
    const int bh = (slot >> 3) * 8 + xcd;
    const int b = bh >> 3, h = bh & 7;
    const int tid = threadIdx.x, lane = tid & 63, w = tid >> 6;   // w 0..7
    const int c = lane & 15, Q = lane >> 4;
    const int c7 = c & 7;

    __shared__ __align__(16) short Ks[8192];   // 16 KB swizzled K tile
    __shared__ __align__(16) short Vs[8192];   // 16 KB interleaved V tile

    // Q fragments: 2 sub-tiles (t) x 2 k-halves, loop-invariant, from global
    const int qbase0 = qt * 256 + w * 32;      // + t*16 + c = q row
    short8 qf[2][2];
#pragma unroll
    for (int t = 0; t < 2; ++t) {
        const short* qb = qh + ((size_t)(b * SS + qbase0 + t * 16 + c)) * HD + h * 64;
        qf[t][0] = *(const short8*)(qb + 8 * Q);
        qf[t][1] = *(const short8*)(qb + 32 + 8 * Q);
    }
    const unsigned* mrow[2] = {
        mbits + (size_t)(b * SS + qbase0 + c) * 64,
        mbits + (size_t)(b * SS + qbase0 + 16 + c) * 64};

    const short* kbase = khS + (size_t)bh * 131072;
    const short* vbase = vI + (size_t)bh * 131072;

    floatx4 o[2][4] = {};
    float m_i[2] = {-INFINITY, -INFINITY}, l_i[2] = {0.f, 0.f};

    for (int kt = 0; kt < 16; ++kt) {
        // ---- stage K (16KB) and V (16KB): flat copies, conflict-free ----
        const short* kg = kbase + kt * 8192;
        const short* vg = vbase + kt * 8192;
#pragma unroll
        for (int it = 0; it < 2; ++it) {
            int off = (it * 512 + tid) * 8;
            *(uint4*)&Ks[off] = *(const uint4*)(kg + off);
            *(uint4*)&Vs[off] = *(const uint4*)(vg + off);
        }
        uint4 mr[2];
#pragma unroll
        for (int t = 0; t < 2; ++t) mr[t] = *(const uint4*)(mrow[t] + kt * 4);
        __syncthreads();

        // ---- S^T = K Q^T for both q-subtiles; K-frags read once ----
        floatx4 s[2][8];
        float mx[2] = {-INFINITY, -INFINITY};
#pragma unroll
        for (int jt = 0; jt < 8; ++jt) {
            short8 k0 = *(const short8*)&Ks[(16 * jt + c) * 64 + ((Q) ^ c7) * 8];
            short8 k1 = *(const short8*)&Ks[(16 * jt + c) * 64 + ((Q + 4) ^ c7) * 8];
#pragma unroll
            for (int t = 0; t < 2; ++t) {
                floatx4 z = {};
                z = __builtin_amdgcn_mfma_f32_16x16x32_bf16(k0, qf[t][0], z, 0, 0, 0);
                z = __builtin_amdgcn_mfma_f32_16x16x32_bf16(k1, qf[t][1], z, 0, 0, 0);
                unsigned mwd = (jt & 2) ? ((jt & 4) ? mr[t].w : mr[t].y)
                                        : ((jt & 4) ? mr[t].z : mr[t].x);
                unsigned nib = (mwd >> (((jt & 1) << 4) + 4 * Q)) & 0xFu;
#pragma unroll
                for (int r = 0; r < 4; ++r) {
                    float val = (nib & (1u << r)) ? -INFINITY : z[r];
                    z[r] = val;
                    mx[t] = fmaxf(mx[t], val);
                }
                s[t][jt] = z;
            }
        }

        // ---- online softmax state update (per-lane; quad-reduce) ----
        float al[2], msafe[2];
#pragma unroll
        for (int t = 0; t < 2; ++t) {
            float m = mx[t];
            m = fmaxf(m, __shfl_xor(m, 16));
            m = fmaxf(m, __shfl_xor(m, 32));
            float mnew = fmaxf(m_i[t], m);
            msafe[t] = (mnew == -INFINITY) ? 0.f : mnew;
            al[t] = __builtin_amdgcn_exp2f(m_i[t] - msafe[t]);
            m_i[t] = mnew;
            // rescale O: need al for q-local 4Q+r (state lives at lane c==4Q+r)
#pragma unroll
            for (int r = 0; r < 4; ++r) {
                float alr = __shfl(al[t], 4 * Q + r);
#pragma unroll
                for (int nt = 0; nt < 4; ++nt) o[t][nt][r] *= alr;
            }
        }

        // ---- P = exp2(S - m); feed directly into PV (16x16x16 MFMA) ----
        float ps[2] = {0.f, 0.f};
#pragma unroll
        for (int jt = 0; jt < 8; ++jt) {
            short4v af[2];
#pragma unroll
            for (int t = 0; t < 2; ++t) {
                float p0 = __builtin_amdgcn_exp2f(s[t][jt][0] - msafe[t]);
                float p1 = __builtin_amdgcn_exp2f(s[t][jt][1] - msafe[t]);
                float p2 = __builtin_amdgcn_exp2f(s[t][jt][2] - msafe[t]);
                float p3 = __builtin_amdgcn_exp2f(s[t][jt][3] - msafe[t]);
                ps[t] += (p0 + p1) + (p2 + p3);
                af[t] = pack4bf_s4(p0, p1, p2, p3);
            }
            const int g = 2 * jt + (Q >> 1);
            const int i4 = 4 * (Q & 1);
#pragma unroll
            for (int nt = 0; nt < 4; ++nt) {
                short4v vf = *(const short4v*)&Vs[g * 512 + ((16 * nt + c) ^ g) * 8 + i4];
                o[0][nt] = mfma16(af[0], vf, o[0][nt]);
                o[1][nt] = mfma16(af[1], vf, o[1][nt]);
            }
        }
#pragma unroll
        for (int t = 0; t < 2; ++t) {
            float p = ps[t];
            p += __shfl_xor(p, 16);
            p += __shfl_xor(p, 32);
            l_i[t] = l_i[t] * al[t] + p;
        }
        __syncthreads();   // tiles dead; safe to restage
    }

    // ---- epilogue: O/l -> y bf16 ----
#pragma unroll
    for (int t = 0; t < 2; ++t) {
#pragma unroll
        for (int r = 0; r < 4; ++r) {
            float lr = __shfl(l_i[t], 4 * Q + r);
            float inv = 1.0f / lr;
            int row = qbase0 + t * 16 + 4 * Q + r;
#pragma unroll
            for (int nt = 0; nt < 4; ++nt)
                y[((size_t)(b * SS + row)) * HD + h * 64 + 16 * nt + c] =
                    f2bf(o[t][nt][r] * inv);
        }
    }
}

// ---------------------------------------------------------------------------
extern "C" void kernel_launch(void* const* d_in, const int* in_sizes, int n_in,
                              void* d_out, int out_size, void* d_ws, size_t ws_size,
                              hipStream_t stream) {
    const float* q    = (const float*)d_in[0];
    const float* k    = (const float*)d_in[1];
    const float* v    = (const float*)d_in[2];
    const float* mask = (const float*)d_in[3];
    const float* Wq   = (const float*)d_in[4];
    const float* bq   = (const float*)d_in[5];
    const float* Wo   = (const float*)d_in[6];
    const float* bo   = (const float*)d_in[7];

    char* ws = (char*)d_ws;
    const size_t MB = 1ull << 20;
    short* WqT = (short*)(ws + 0 * MB);    // 64 KB
    short* WoT = (short*)(ws + 1 * MB);    // 512 KB
    short* qh  = (short*)(ws + 8 * MB);    // 16 MB  [b][s][hd], pre-scaled log2e/8
    short* khS = (short*)(ws + 24 * MB);   // 16 MB  swizzled [bh][s][dg^s&7][8]
    short* vI  = (short*)(ws + 40 * MB);   // 16 MB  interleaved [bh][s8][d^sg][8]
    unsigned long long* bits = (unsigned long long*)(ws + 56 * MB);  // 4 MB
    short* yb  = (short*)(ws + 60 * MB);   // 16 MB  [b][s][hd]
    float* out = (float*)d_out;

    const float ALPHA_Q = 0.18033688011f;  // log2(e)/8

    prep_kernel<<<1024, 256, 0, stream>>>(Wq, Wo, WqT, WoT);
    maskbits_kernel<<<32768, 256, 0, stream>>>(mask, bits);

    // qh = (q @ Wq + bq) * alpha   (natural layout)
    gemm_bt<1, false, true, false><<<dim3(4, 128, 1), 256, 0, stream>>>(
        q, 64, 0, WqT, 64, 0, (void*)qh, 512, 0, bq, 64, ALPHA_Q);
    // khS = swizzled(k @ Wq + bq)
    gemm_bt<2, false, true, false><<<dim3(4, 128, 1), 256, 0, stream>>>(
        k, 64, 0, WqT, 64, 0, (void*)khS, 0, 0, bq, 64, 1.0f);
    // vI = interleaved(WqT @ v^T + bq), batched over b
    gemm_bt<3, true, false, true><<<dim3(16, 4, BB), 256, 0, stream>>>(
        WqT, 64, 0, v, 64, (long)SS * 64, (void*)vI, 0, 0, bq, 64, 1.0f);

    fa_kernel<<<dim3(512, 1, 1), 512, 0, stream>>>(qh, khS, vI, (const unsigned*)bits, yb);

    // out = y @ Wo + bo  (fp32)
    gemm_bt<0, false, false, false><<<dim3(4, 128, 1), 256, 0, stream>>>(
        yb, 512, 0, WoT, 512, 0, (void*)out, 512, 0, bo, 512, 1.0f);
}